// Round 8
// baseline (2918.729 us; speedup 1.0000x reference)
//
#include <hip/hip_runtime.h>

// ---------------------------------------------------------------------------
// 3-layer SimpleRNN, B=256 T=512 U=512 E=128, fp16 MFMA.
// R8 = R5 protocol (proven correct, 2632us) +
//  (1) XOR LDS/global layout: chunk c of row r lives at pos c^(r&7).
//      Fragment reads hit the 8-lane/bank-quad floor (R5's rotation swizzle
//      was 2x floor -> 6.1e7 bank conflicts).
//  (2) Ain (upstream tile) streamed via async global_load_lds DMA, issued
//      after sibling staging, drained after the Wh GEMM -> its bytes leave
//      the serial L3 round-trip chain.
//  (3) raw barriers (s_waitcnt lgkmcnt(0); s_barrier) so the DMA stays in
//      flight across the staging barrier (__syncthreads would drain vmcnt).
//  (4) chunked Bounce->Ah epilogue; mg-staggered start; R6 gather prefetch.
// ---------------------------------------------------------------------------

#define BATCH 256
#define SEQ   512
#define EMBD  128
#define UNIT  512

typedef _Float16 half8 __attribute__((ext_vector_type(8)));
typedef _Float16 half4 __attribute__((ext_vector_type(4)));
typedef float    f32x4 __attribute__((ext_vector_type(4)));
typedef unsigned int uint4v __attribute__((ext_vector_type(4)));
typedef int      int4v __attribute__((ext_vector_type(4)));

// ws layout (bytes). Total ~4.63 MB.
#define FLAGS_BYTES 4096
#define HBUF_OFF    4096
#define HBUF_ELEMS  (3*8*4*32*512)          // [layer][mgroup][slot][32][512] f16
#define HBUF_BYTES  (HBUF_ELEMS*2)
#define PWX0_OFF    (HBUF_OFF + HBUF_BYTES)
#define PWH0_OFF    (PWX0_OFF + EMBD*UNIT*2)
#define PWX1_OFF    (PWH0_OFF + UNIT*UNIT*2)
#define PWH1_OFF    (PWX1_OFF + UNIT*UNIT*2)

// ---------------------------------------------------------------------------
__device__ __forceinline__ void sc_st_int(int* p, int v) {
    asm volatile("global_store_dword %0, %1, off sc0 sc1" :: "v"(p), "v"(v) : "memory");
}

// three flag quads in one round trip (combined issue+wait: sound)
__device__ __forceinline__ void sc_ld_q3(const int* p0, const int* p1, const int* p2,
                                         int4v& a, int4v& b, int4v& c) {
    asm volatile(
        "global_load_dwordx4 %0, %3, off sc0 sc1\n\t"
        "global_load_dwordx4 %1, %4, off sc0 sc1\n\t"
        "global_load_dwordx4 %2, %5, off sc0 sc1\n\t"
        "s_waitcnt vmcnt(0)"
        : "=&v"(a), "=&v"(b), "=&v"(c)
        : "v"(p0), "v"(p1), "v"(p2)
        : "memory");
}

__device__ __forceinline__ void sc_load6(
    const uint4v* p0, const uint4v* p1, const uint4v* p2,
    const uint4v* p3, const uint4v* p4, const uint4v* p5,
    uint4v& r0, uint4v& r1, uint4v& r2, uint4v& r3, uint4v& r4, uint4v& r5)
{
    asm volatile(
        "global_load_dwordx4 %0, %6, off sc0 sc1\n\t"
        "global_load_dwordx4 %1, %7, off sc0 sc1\n\t"
        "global_load_dwordx4 %2, %8, off sc0 sc1\n\t"
        "global_load_dwordx4 %3, %9, off sc0 sc1\n\t"
        "global_load_dwordx4 %4, %10, off sc0 sc1\n\t"
        "global_load_dwordx4 %5, %11, off sc0 sc1\n\t"
        "s_waitcnt vmcnt(0)"
        : "=&v"(r0), "=&v"(r1), "=&v"(r2), "=&v"(r3), "=&v"(r4), "=&v"(r5)
        : "v"(p0), "v"(p1), "v"(p2), "v"(p3), "v"(p4), "v"(p5)
        : "memory");
}

__device__ __forceinline__ void sc_store2(uint4v* p0, uint4v v0, uint4v* p1, uint4v v1) {
    asm volatile(
        "global_store_dwordx4 %0, %2, off sc0 sc1\n\t"
        "global_store_dwordx4 %1, %3, off sc0 sc1\n\t"
        "s_waitcnt vmcnt(0)"
        :: "v"(p0), "v"(p1), "v"(v0), "v"(v1)
        : "memory");
}

// raw barrier: LDS-drain only, leaves vmcnt (DMA/gathers) in flight
__device__ __forceinline__ void bar_lgkm() {
    asm volatile("s_waitcnt lgkmcnt(0)\n\ts_barrier" ::: "memory");
}
// barrier that also drains this wave's VMEM (DMA completion)
__device__ __forceinline__ void bar_vm_lgkm() {
    asm volatile("s_waitcnt vmcnt(0) lgkmcnt(0)\n\ts_barrier" ::: "memory");
}
// plain barrier (no drains)
__device__ __forceinline__ void bar_only() {
    asm volatile("s_barrier" ::: "memory");
}

// async global -> LDS, 16B/lane, sc0|sc1 cache policy (CPol SC0=1, SC1=16)
__device__ __forceinline__ void lds_dma16(const void* g, void* l) {
    __builtin_amdgcn_global_load_lds(
        (const __attribute__((address_space(1))) void*)g,
        (__attribute__((address_space(3))) void*)l,
        16, 0, 17);
}

// ---------------------------------------------------------------------------
__global__ void zero_ws_kernel(uint4v* __restrict__ p, int n16) {
    int i = blockIdx.x * 256 + threadIdx.x;
    uint4v z = {0u, 0u, 0u, 0u};
    if (i < n16) p[i] = z;
}

// Pack fp32 weight [K][N] into MFMA B-fragment order, fp16:
// dst[((nt*KT + kt)*64 + lane)*8 + j] = W[kt*32 + (lane>>4)*8 + j][nt*16 + (lane&15)]
__global__ void pack_w_kernel(const float* __restrict__ src, _Float16* __restrict__ dst,
                              int K, int N) {
    int idx = blockIdx.x * 256 + threadIdx.x;
    if (idx >= K * N) return;
    int j    = idx & 7;
    int lane = (idx >> 3) & 63;
    int rest = idx >> 9;
    int KT   = K >> 5;
    int kt   = rest % KT;
    int nt   = rest / KT;
    int k = kt*32 + (lane >> 4)*8 + j;
    int n = nt*16 + (lane & 15);
    dst[idx] = (_Float16)src[k * N + n];
}

// ---------------------------------------------------------------------------
__global__ __launch_bounds__(256, 1)
void rnn_main_kernel(const int*   __restrict__ tokens,
                     const float* __restrict__ emb,
                     const float* __restrict__ b0,
                     const float* __restrict__ b1,
                     char* ws)
{
    const int bid   = blockIdx.x;
    const int layer = bid >> 5;          // 0..2
    const int mg    = (bid >> 2) & 7;    // batch group (32 rows)
    const int ns    = bid & 3;           // N-strip (128 cols)
    const int tid   = threadIdx.x;
    const int wv    = tid >> 6;
    const int lane  = tid & 63;
    const int q     = lane >> 4;         // quad
    const int c16   = lane & 15;
    const int xq    = c16 & 7;           // XOR-layout key for fragment reads

    // stagger the 8 independent batch-groups' memory bursts (~0.45us per mg)
    for (int i = 0; i < mg; ++i) { __builtin_amdgcn_s_sleep(8); __builtin_amdgcn_s_sleep(8); }

    int* flags = (int*)ws;               // quad per (layer,mg), 128B apart
    int* qOwn  = flags + (layer*8 + mg)*32;
    int* qUp   = flags + ((layer > 0 ? layer-1 : layer)*8 + mg)*32;
    int* qDn   = flags + ((layer < 2 ? layer+1 : layer)*8 + mg)*32;

    _Float16* hbuf = (_Float16*)(ws + HBUF_OFF);
    const _Float16* pWh = (const _Float16*)(ws + (layer == 0 ? PWH0_OFF : PWH1_OFF));
    const _Float16* pWx = (const _Float16*)(ws + (layer == 0 ? PWX0_OFF : PWX1_OFF));
    const float* bias = (layer == 0) ? b0 : b1;

    const int c0  = ns*128 + wv*32;      // global col base of this wave
    const int nt0 = c0 >> 4;

    // LDS 72KB. Layout: chunk c (16B) of row r at byte r*1024 + (c^(r&7))*16.
    // Global ring tiles use the SAME per-row permutation -> staging and DMA
    // are identity copies, and fragment reads hit the bank-quad floor.
    __shared__ _Float16 Ah [32][512];    // h_l(t-1) A-tile
    __shared__ _Float16 Ain[32][512];    // input A-tile (x_t or h_{l-1}(t))
    __shared__ _Float16 Bounce[32][128]; // strip tile (logical layout)

    // zero Ah: h(-1) = 0
    {
        uint4v z = {0u,0u,0u,0u};
#pragma unroll
        for (int i = 0; i < 8; ++i) ((uint4v*)Ah)[i*256 + tid] = z;
    }

    // ---- register-resident weights (B-fragments) ----
    half8 whf[16][2];
    half8 wxf[16][2];
#pragma unroll
    for (int kt = 0; kt < 16; ++kt)
#pragma unroll
        for (int n = 0; n < 2; ++n)
            whf[kt][n] = *(const half8*)&pWh[(((nt0 + n)*16 + kt)*64 + lane) * 8];
    if (layer == 0) {
#pragma unroll
        for (int kt = 0; kt < 4; ++kt)
#pragma unroll
            for (int n = 0; n < 2; ++n)
                wxf[kt][n] = *(const half8*)&pWx[(((nt0 + n)*4 + kt)*64 + lane) * 8];
    } else {
#pragma unroll
        for (int kt = 0; kt < 16; ++kt)
#pragma unroll
            for (int n = 0; n < 2; ++n)
                wxf[kt][n] = *(const half8*)&pWx[(((nt0 + n)*16 + kt)*64 + lane) * 8];
    }

    const float bv0 = bias[c0 + c16];
    const float bv1 = bias[c0 + 16 + c16];

    const int m0       = mg * 32;
    const int slotBase = (layer*8 + mg) * 4;

    // sibling strip ids (the 3 strips != ns, ascending)
    const int sA = (ns == 0) ? 1 : 0;
    const int sB = (ns <= 1) ? 2 : 1;
    const int sC = (ns <= 2) ? 3 : 2;

    // per-thread chunk pair for staging / epilogue (j in [0,512))
    const int j0 = 2*tid, j1 = j0 + 1;
    const int r0i = j0 >> 4, cl0 = j0 & 15;
    const int r1i = j1 >> 4, cl1 = j1 & 15;
    const int k0 = r0i & 7, k1 = r1i & 7;      // XOR keys of those rows
    // physical positions of sibling chunks (16-aligned blocks are XOR-closed)
    const int pA0 = sA*16 + cl0, pA1 = sA*16 + cl1;
    const int pB0 = sB*16 + cl0, pB1 = sB*16 + cl1;
    const int pC0 = sC*16 + cl0, pC1 = sC*16 + cl1;
    // own-strip physical positions for the epilogue
    const int pO0 = (ns*16 + cl0) ^ k0;
    const int pO1 = (ns*16 + cl1) ^ k1;

    // ---- layer 0: pre-stage x_0 -> Ain (chunks 0..15, XOR layout) ----
    if (layer == 0) {
#pragma unroll
        for (int i = 0; i < 4; ++i) {
            int idx = i*256 + tid;           // 1024 float4 (= half-chunk) pieces
            int r   = idx >> 5;
            int qq  = idx & 31;
            int tok = tokens[(m0 + r)*SEQ + 0];
            float4 f = *((const float4*)(emb + (long)tok * EMBD) + qq);
            half4 h = { (_Float16)f.x, (_Float16)f.y, (_Float16)f.z, (_Float16)f.w };
            int pc = (qq >> 1) ^ (r & 7);
            *(half4*)&Ain[r][pc*8 + (qq & 1)*4] = h;
        }
    }
    __syncthreads();

    for (int t = 0; t < SEQ; ++t) {
        // ---- poll (1 RT): own >= t, up >= t+1, down >= t-3 ----
        if (tid == 0) {
            for (;;) {
                int4v o, u, d;
                sc_ld_q3(qOwn, qUp, qDn, o, u, d);
                int mo = o[0] < o[1] ? o[0] : o[1];
                mo = mo < o[2] ? mo : o[2]; mo = mo < o[3] ? mo : o[3];
                int mu = u[0] < u[1] ? u[0] : u[1];
                mu = mu < u[2] ? mu : u[2]; mu = mu < u[3] ? mu : u[3];
                int md = d[0] < d[1] ? d[0] : d[1];
                md = md < d[2] ? md : d[2]; md = md < d[3] ? md : d[3];
                bool ok = (mo >= t);
                if (layer > 0)            ok = ok && (mu >= t + 1);
                if (layer < 2 && t >= 4)  ok = ok && (md >= t - 3);
                if (ok) break;
                __builtin_amdgcn_s_sleep(1);
            }
        }
        bar_only();        // (B) deps satisfied

        const uint4v* tp = (const uint4v*)(hbuf + (slotBase + ((t + 3) & 3)) * 16384);

        // ---- sibling chunks: load (1 RT) + identity-stage into Ah ----
        {
            uint4v s0, s1, s2, s3, s4, s5;
            sc_load6(tp + r0i*64 + pA0, tp + r1i*64 + pA1,
                     tp + r0i*64 + pB0, tp + r1i*64 + pB1,
                     tp + r0i*64 + pC0, tp + r1i*64 + pC1,
                     s0, s1, s2, s3, s4, s5);
            *(uint4v*)&Ah[r0i][pA0 * 8] = s0;
            *(uint4v*)&Ah[r1i][pA1 * 8] = s1;
            *(uint4v*)&Ah[r0i][pB0 * 8] = s2;
            *(uint4v*)&Ah[r1i][pB1 * 8] = s3;
            *(uint4v*)&Ah[r0i][pC0 * 8] = s4;
            *(uint4v*)&Ah[r1i][pC1 * 8] = s5;
        }

        float4 pg0, pg1, pg2, pg3;           // layer-0 gather prefetch (t+1)
        if (layer > 0) {
            // ---- issue Ain DMA (async; overlaps Wh GEMM) ----
            const _Float16* sb = hbuf + (((layer-1)*8 + mg)*4 + (t & 3)) * 16384;
#pragma unroll
            for (int i = 0; i < 8; ++i) {
                int row = wv*8 + i;
                lds_dma16(sb + row*512 + lane*8, &Ain[row][0]);
            }
        } else {
            // issue embedding gather for t+1 (plain cached loads; consumed
            // between barriers D and E)
            int tn = (t + 1 < SEQ) ? t + 1 : SEQ - 1;
            int idx0 = tid,        r0g = idx0 >> 5, q0g = idx0 & 31;
            int idx1 = 256 + tid,  r1g = idx1 >> 5, q1g = idx1 & 31;
            int idx2 = 512 + tid,  r2g = idx2 >> 5, q2g = idx2 & 31;
            int idx3 = 768 + tid,  r3g = idx3 >> 5, q3g = idx3 & 31;
            int t0 = tokens[(m0 + r0g)*SEQ + tn];
            int t1 = tokens[(m0 + r1g)*SEQ + tn];
            int t2 = tokens[(m0 + r2g)*SEQ + tn];
            int t3 = tokens[(m0 + r3g)*SEQ + tn];
            pg0 = *((const float4*)(emb + (long)t0 * EMBD) + q0g);
            pg1 = *((const float4*)(emb + (long)t1 * EMBD) + q1g);
            pg2 = *((const float4*)(emb + (long)t2 * EMBD) + q2g);
            pg3 = *((const float4*)(emb + (long)t3 * EMBD) + q3g);
        }

        bar_lgkm();        // (C) Ah staged; DMA/gathers stay in flight

        f32x4 acc00 = {0,0,0,0}, acc01 = {0,0,0,0}, acc10 = {0,0,0,0}, acc11 = {0,0,0,0};

        // ---- Wh GEMM (reads Ah, XOR layout, bank-quad floor) ----
#pragma unroll
        for (int kt = 0; kt < 16; ++kt) {
            half8 a0 = *(const half8*)&Ah[c16]     [((kt*4 + q) ^ xq) * 8];
            half8 a1 = *(const half8*)&Ah[16 + c16][((kt*4 + q) ^ xq) * 8];
            acc00 = __builtin_amdgcn_mfma_f32_16x16x32_f16(a0, whf[kt][0], acc00, 0, 0, 0);
            acc01 = __builtin_amdgcn_mfma_f32_16x16x32_f16(a0, whf[kt][1], acc01, 0, 0, 0);
            acc10 = __builtin_amdgcn_mfma_f32_16x16x32_f16(a1, whf[kt][0], acc10, 0, 0, 0);
            acc11 = __builtin_amdgcn_mfma_f32_16x16x32_f16(a1, whf[kt][1], acc11, 0, 0, 0);
        }

        // ---- Wx GEMM ----
        if (layer > 0) {
            bar_vm_lgkm();     // (C2) every wave's DMA drained -> Ain complete
#pragma unroll
            for (int kt = 0; kt < 16; ++kt) {
                half8 a0 = *(const half8*)&Ain[c16]     [((kt*4 + q) ^ xq) * 8];
                half8 a1 = *(const half8*)&Ain[16 + c16][((kt*4 + q) ^ xq) * 8];
                acc00 = __builtin_amdgcn_mfma_f32_16x16x32_f16(a0, wxf[kt][0], acc00, 0, 0, 0);
                acc01 = __builtin_amdgcn_mfma_f32_16x16x32_f16(a0, wxf[kt][1], acc01, 0, 0, 0);
                acc10 = __builtin_amdgcn_mfma_f32_16x16x32_f16(a1, wxf[kt][0], acc10, 0, 0, 0);
                acc11 = __builtin_amdgcn_mfma_f32_16x16x32_f16(a1, wxf[kt][1], acc11, 0, 0, 0);
            }
        } else {
#pragma unroll
            for (int kt = 0; kt < 4; ++kt) {
                half8 a0 = *(const half8*)&Ain[c16]     [((kt*4 + q) ^ xq) * 8];
                half8 a1 = *(const half8*)&Ain[16 + c16][((kt*4 + q) ^ xq) * 8];
                acc00 = __builtin_amdgcn_mfma_f32_16x16x32_f16(a0, wxf[kt][0], acc00, 0, 0, 0);
                acc01 = __builtin_amdgcn_mfma_f32_16x16x32_f16(a0, wxf[kt][1], acc01, 0, 0, 0);
                acc10 = __builtin_amdgcn_mfma_f32_16x16x32_f16(a1, wxf[kt][0], acc10, 0, 0, 0);
                acc11 = __builtin_amdgcn_mfma_f32_16x16x32_f16(a1, wxf[kt][1], acc11, 0, 0, 0);
            }
        }

        // ---- tanh -> Bounce (disjoint per-wave) ----
#pragma unroll
        for (int r = 0; r < 4; ++r) {
            int row0 = q*4 + r, row1 = 16 + row0;
            float z, e;
            z = acc00[r] + bv0; e = __expf(2.0f*z);
            Bounce[row0][wv*32 + c16]      = (_Float16)(1.0f - 2.0f/(e + 1.0f));
            z = acc01[r] + bv1; e = __expf(2.0f*z);
            Bounce[row0][wv*32 + 16 + c16] = (_Float16)(1.0f - 2.0f/(e + 1.0f));
            z = acc10[r] + bv0; e = __expf(2.0f*z);
            Bounce[row1][wv*32 + c16]      = (_Float16)(1.0f - 2.0f/(e + 1.0f));
            z = acc11[r] + bv1; e = __expf(2.0f*z);
            Bounce[row1][wv*32 + 16 + c16] = (_Float16)(1.0f - 2.0f/(e + 1.0f));
        }
        bar_lgkm();        // (D) Bounce complete; all Ah/Ain reads done

        // ---- epilogue: Bounce -> Ah(t) own strip (chunked) + ring store ----
        {
            uint4v v0 = *(const uint4v*)&Bounce[r0i][cl0 * 8];
            uint4v v1 = *(const uint4v*)&Bounce[r1i][cl1 * 8];
            *(uint4v*)&Ah[r0i][pO0 * 8] = v0;
            *(uint4v*)&Ah[r1i][pO1 * 8] = v1;
            if (layer == 0 && t + 1 < SEQ) {
#pragma unroll
                for (int i = 0; i < 4; ++i) {
                    float4 f = (i==0)?pg0:(i==1)?pg1:(i==2)?pg2:pg3;
                    int idx = i*256 + tid;
                    int r   = idx >> 5;
                    int qq  = idx & 31;
                    half4 h = { (_Float16)f.x, (_Float16)f.y, (_Float16)f.z, (_Float16)f.w };
                    int pc = (qq >> 1) ^ (r & 7);
                    *(half4*)&Ain[r][pc*8 + (qq & 1)*4] = h;
                }
            }
            _Float16* tc = hbuf + (slotBase + (t & 3)) * 16384;
            sc_store2((uint4v*)(tc + r0i*512) + pO0, v0,
                      (uint4v*)(tc + r1i*512) + pO1, v1);
        }
        bar_lgkm();        // (E) Ah(t)/Ain(t+1) done; all lanes' stores drained
        if (tid == 0) sc_st_int(qOwn + ns, t + 1);
    }
}

// ---------------------------------------------------------------------------
// logits = h2(T-1) @ fc_w + fc_b ; out = sigmoid(logits). One wave per row.
// Ring tiles are stored XOR-permuted: physical chunk p of row r holds
// logical chunk p^(r&7) -> index fc_w accordingly.
__global__ void fc_kernel(const char* __restrict__ ws,
                          const float* __restrict__ fc_w,
                          const float* __restrict__ fc_b,
                          float* __restrict__ out)
{
    int row  = blockIdx.x;
    int lane = threadIdx.x;          // 64
    int m = row >> 5, lr = row & 31;
    const _Float16* h2 = (const _Float16*)(ws + HBUF_OFF)
                         + (((2*8 + m)*4 + 3) * 16384)   // slot 511&3 = 3
                         + lr * UNIT;
    half8 hv = *(const half8*)&h2[lane * 8];
    int c = lane ^ (lr & 7);                 // logical chunk held by this lane
    const float* w = fc_w + c * 8;
    float s = 0.0f;
#pragma unroll
    for (int j = 0; j < 8; ++j) s += (float)hv[j] * w[j];
#pragma unroll
    for (int off = 32; off > 0; off >>= 1) s += __shfl_down(s, off);
    if (lane == 0) {
        float logit = s + fc_b[0];
        out[row] = 1.0f / (1.0f + __expf(-logit));
    }
}

// ---------------------------------------------------------------------------
extern "C" void kernel_launch(void* const* d_in, const int* in_sizes, int n_in,
                              void* d_out, int out_size, void* d_ws, size_t ws_size,
                              hipStream_t stream)
{
    const int*   tokens = (const int*)  d_in[0];
    const float* emb    = (const float*)d_in[1];
    const float* Wx0    = (const float*)d_in[2];
    const float* Wh0    = (const float*)d_in[3];
    const float* b0     = (const float*)d_in[4];
    const float* Wx1    = (const float*)d_in[5];
    const float* Wh1    = (const float*)d_in[6];
    const float* b1     = (const float*)d_in[7];
    const float* fcw    = (const float*)d_in[8];
    const float* fcb    = (const float*)d_in[9];
    char*  ws  = (char*)d_ws;
    float* out = (float*)d_out;

    // 1) zero flags + h ring (t=0 reads ring slot 3 as h(-1)=0)
    int n16 = (FLAGS_BYTES + HBUF_BYTES) / 16;
    zero_ws_kernel<<<(n16 + 255)/256, 256, 0, stream>>>((uint4v*)ws, n16);

    // 2) pack weights fp32 -> fp16 B-fragment layout
    pack_w_kernel<<<(EMBD*UNIT + 255)/256, 256, 0, stream>>>(Wx0, (_Float16*)(ws + PWX0_OFF), EMBD, UNIT);
    pack_w_kernel<<<(UNIT*UNIT + 255)/256, 256, 0, stream>>>(Wh0, (_Float16*)(ws + PWH0_OFF), UNIT, UNIT);
    pack_w_kernel<<<(UNIT*UNIT + 255)/256, 256, 0, stream>>>(Wx1, (_Float16*)(ws + PWX1_OFF), UNIT, UNIT);
    pack_w_kernel<<<(UNIT*UNIT + 255)/256, 256, 0, stream>>>(Wh1, (_Float16*)(ws + PWH1_OFF), UNIT, UNIT);

    // 3) pipelined recurrence: 96 blocks = 3 layers x 8 batch-groups x 4 N-strips
    rnn_main_kernel<<<96, 256, 0, stream>>>(tokens, emb, b0, b1, ws);

    // 4) final FC + sigmoid
    fc_kernel<<<256, 64, 0, stream>>>((const char*)ws, fcw, fcb, out);
}